// Round 2
// baseline (1049.910 us; speedup 1.0000x reference)
//
#include <hip/hip_runtime.h>
#include <cstdint>

#define BM 128
#define BN 128
#define BK 32

typedef __attribute__((ext_vector_type(8))) short short8;
typedef _Float16 half8 __attribute__((ext_vector_type(8)));
typedef __attribute__((ext_vector_type(4))) float floatx4;

union H8 { short8 s; half8 h; };

static constexpr float SIBS   = 0.044194173824159216f; // 1/sqrt(512)
static constexpr float LS_INV = 1.0f / 2048.0f;

__device__ __forceinline__ unsigned short f2bf(float x){
    union { float f; unsigned u32; } v; v.f = x;
    unsigned r = ((v.u32 >> 16) & 1u) + 0x7fffu;
    return (unsigned short)((v.u32 + r) >> 16);
}
__device__ __forceinline__ void split_f16(float x, unsigned short& h, unsigned short& s){
    _Float16 hh = (_Float16)x;
    _Float16 ss = (_Float16)((x - (float)hh) * 2048.0f);
    union { _Float16 f; unsigned short u; } a, b;
    a.f = hh; b.f = ss;
    h = a.u; s = b.u;
}

#define GLDS(g, l) __builtin_amdgcn_global_load_lds( \
    (const __attribute__((address_space(1))) void*)(g), \
    (__attribute__((address_space(3))) void*)(l), 16, 0, 0)

// ---- prep: fp32 src[R][C] -> transposed fp16 hi/lo-scaled pair [C][R] ----
__global__ void prep_split16_T(const float* __restrict__ src,
                               unsigned short* __restrict__ hiT,
                               unsigned short* __restrict__ lsT,
                               int R, int C)
{
    __shared__ float t[32][33];
    int c0 = blockIdx.x * 32, r0 = blockIdx.y * 32;
    int tx = threadIdx.x & 31, ty = threadIdx.x >> 5;
#pragma unroll
    for (int k = 0; k < 4; k++){
        int r = ty + k*8;
        t[r][tx] = src[(size_t)(r0 + r) * C + c0 + tx];
    }
    __syncthreads();
#pragma unroll
    for (int k = 0; k < 4; k++){
        int r = ty + k*8;
        float x = t[tx][r]; // = src[r0+tx][c0+r]
        unsigned short h, s;
        split_f16(x, h, s);
        size_t o = (size_t)(c0 + r) * R + r0 + tx;
        hiT[o] = h; lsT[o] = s;
    }
}

// ---- prep: fp32 src[R][C] -> transposed bf16 [C][R] ----
__global__ void prep_bf16_T(const float* __restrict__ src,
                            unsigned short* __restrict__ dstT,
                            int R, int C)
{
    __shared__ float t[32][33];
    int c0 = blockIdx.x * 32, r0 = blockIdx.y * 32;
    int tx = threadIdx.x & 31, ty = threadIdx.x >> 5;
#pragma unroll
    for (int k = 0; k < 4; k++){
        int r = ty + k*8;
        t[r][tx] = src[(size_t)(r0 + r) * C + c0 + tx];
    }
    __syncthreads();
#pragma unroll
    for (int k = 0; k < 4; k++){
        int r = ty + k*8;
        dstT[(size_t)(c0 + r) * R + r0 + tx] = f2bf(t[tx][r]);
    }
}

// ---------------- unified GEMM ----------------
// MODE 0: h0   — A = gathered emb rows (fp32 -> fp16 2-limb), writes nodes0(f32out) + agg
// MODE 1: tree — A = fp32 nodes (fp16 2-limb), +bc+sib, write nodes_next (DEPTH<2),
//                masked atomicAdd into agg
// MODE 2: out  — A = pooled (bf16), B = WoutT (bf16), write fp32 logits (+bout)
// B pre-transposed [N][K], K=512. MODE<=1: BTh/BTl fp16 pair; MODE 2: BTh bf16.
template<int MODE, int DEPTH>
__global__ __launch_bounds__(256, 2)
void gemm_k(const unsigned short* __restrict__ Abf,
            const float* __restrict__ Af32,
            const unsigned short* __restrict__ BTh,
            const unsigned short* __restrict__ BTl,
            const float* __restrict__ bias,
            const int* __restrict__ tokens,
            const float* __restrict__ emb,
            const float* __restrict__ sib,
            const unsigned char* __restrict__ eflag,
            float* __restrict__ nodes_next,
            float* __restrict__ agg,
            float* __restrict__ f32out,
            float* __restrict__ out,
            int N)
{
    constexpr int K = 512;
    // fragment-contiguous LDS: slot s = kq*128 + m, 8 elems (16B) per slot
    __shared__ __align__(16) unsigned short Ah[BM*BK];
    __shared__ __align__(16) unsigned short Al[BM*BK];
    __shared__ __align__(16) unsigned short Bh[BK*BN];
    __shared__ __align__(16) unsigned short Bl[BK*BN];

    const int tid = threadIdx.x;
    const int w = tid >> 6, l = tid & 63;
    const int wr = w >> 1, wc = w & 1;
    const int row0 = blockIdx.x * BM;
    const int n0   = blockIdx.y * BN;
    const int q = l >> 4, lm = l & 15;

    floatx4 acc[4][4]  = {};
    floatx4 accx[4][4] = {};

    // A-source row pointer (fp32 modes): thread covers slots (kq0, kq0+2) x row m
    const float* aptr = nullptr;
    const int am = tid & 127, kq0 = tid >> 7;
    if (MODE == 0)      aptr = emb  + (long)tokens[row0 + am] * K;
    else if (MODE == 1) aptr = Af32 + (long)(row0 + am) * K;

    long arow0 = 0, arow1 = 0;
    if (MODE == 2){
        arow0 = (long)(row0 + l) * K;
        arow1 = (long)(row0 + 64 + l) * K;
    }
    const long brow0 = (long)(n0 + l) * K;
    const long brow1 = (long)(n0 + 64 + l) * K;

    for (int k0 = 0; k0 < K; k0 += BK){
        __syncthreads();
        // stage B (hi): wave w covers kq=w, rows l and 64+l
        GLDS(BTh + brow0 + k0 + w*8, (char*)Bh + w*2048);
        GLDS(BTh + brow1 + k0 + w*8, (char*)Bh + w*2048 + 1024);
        if (MODE <= 1){
            GLDS(BTl + brow0 + k0 + w*8, (char*)Bl + w*2048);
            GLDS(BTl + brow1 + k0 + w*8, (char*)Bl + w*2048 + 1024);
            // A: fp32 -> fp16 hi/lo-scaled limbs through VGPRs
#pragma unroll
            for (int t = 0; t < 2; t++){
                int kq = kq0 + 2*t;
                const float* src = aptr + k0 + kq*8;
                float xs[8];
                *(floatx4*)&xs[0] = *(const floatx4*)(src);
                *(floatx4*)&xs[4] = *(const floatx4*)(src + 4);
                unsigned short h8[8], l8[8];
#pragma unroll
                for (int e = 0; e < 8; e++) split_f16(xs[e], h8[e], l8[e]);
                int s = kq*128 + am;
                *(short8*)&Ah[s*8] = *(const short8*)h8;
                *(short8*)&Al[s*8] = *(const short8*)l8;
            }
        } else {
            GLDS(Abf + arow0 + k0 + w*8, (char*)Ah + w*2048);
            GLDS(Abf + arow1 + k0 + w*8, (char*)Ah + w*2048 + 1024);
        }
        __syncthreads();

        H8 bh[4], bl[4];
#pragma unroll
        for (int j = 0; j < 4; j++){
            bh[j].s = *(const short8*)&Bh[(q*128 + wc*64 + j*16 + lm)*8];
            if (MODE <= 1)
                bl[j].s = *(const short8*)&Bl[(q*128 + wc*64 + j*16 + lm)*8];
        }
#pragma unroll
        for (int i = 0; i < 4; i++){
            H8 ah; ah.s = *(const short8*)&Ah[(q*128 + wr*64 + i*16 + lm)*8];
            if (MODE <= 1){
                H8 al; al.s = *(const short8*)&Al[(q*128 + wr*64 + i*16 + lm)*8];
#pragma unroll
                for (int j = 0; j < 4; j++)
                    acc[i][j]  = __builtin_amdgcn_mfma_f32_16x16x32_f16(ah.h, bh[j].h, acc[i][j], 0, 0, 0);
#pragma unroll
                for (int j = 0; j < 4; j++)
                    accx[i][j] = __builtin_amdgcn_mfma_f32_16x16x32_f16(ah.h, bl[j].h, accx[i][j], 0, 0, 0);
#pragma unroll
                for (int j = 0; j < 4; j++)
                    accx[i][j] = __builtin_amdgcn_mfma_f32_16x16x32_f16(al.h, bh[j].h, accx[i][j], 0, 0, 0);
            } else {
#pragma unroll
                for (int j = 0; j < 4; j++)
                    acc[i][j] = __builtin_amdgcn_mfma_f32_16x16x32_bf16(ah.s, bh[j].s, acc[i][j], 0, 0, 0);
            }
        }
    }

    // epilogue: D[row=(l>>4)*4+r][col=l&15] per 16x16 frag
#pragma unroll
    for (int i = 0; i < 4; i++){
        int rbase = row0 + wr*64 + i*16 + q*4;
        unsigned char fl[4];
        if (MODE == 1){
#pragma unroll
            for (int r = 0; r < 4; r++) fl[r] = eflag[rbase + r];
        }
#pragma unroll
        for (int j = 0; j < 4; j++){
            int col = n0 + wc*64 + j*16 + lm;
            float badd = bias[col];
            int half = 0, h = 0;
            if (MODE == 1){
                half = col >> 9; h = col & 511;
                badd += SIBS * sib[half*512 + h];
            }
#pragma unroll
            for (int r = 0; r < 4; r++){
                int row = rbase + r;
                float v = acc[i][j][r];
                if (MODE <= 1) v += accx[i][j][r] * LS_INV;
                v += badd;
                if (MODE == 0){
                    f32out[(long)row*512 + col] = v;
                    agg[(long)row*512 + col]    = v;
                } else if (MODE == 1){
                    if (DEPTH < 2)
                        nodes_next[((long)(2*row + half))*512 + h] = v;
                    if (fl[r])
                        atomicAdd(&agg[((long)(row >> DEPTH))*512 + h], v);
                } else {
                    out[(long)row*(long)N + col] = v;
                }
            }
        }
    }
}

// ---- gate: x = (node + 0.01*dep_d) . Wg + bg ; expand = (x>0) & active ----
__global__ void gate_k(const float* __restrict__ nodes,
                       const float* __restrict__ Wg,
                       const float* __restrict__ bg,
                       const float* __restrict__ deprow,
                       const unsigned char* __restrict__ eprev,
                       unsigned char* __restrict__ e,
                       int depth)
{
    int row = blockIdx.x * 4 + (threadIdx.x >> 6);
    int l = threadIdx.x & 63;
    const float* nr = nodes + (long)row * 512;
    float s = 0.f;
#pragma unroll
    for (int t = 0; t < 8; t++){
        int h = t*64 + l;
        s += (nr[h] + 0.01f * deprow[h]) * Wg[h];
    }
#pragma unroll
    for (int off = 32; off > 0; off >>= 1) s += __shfl_down(s, off);
    if (l == 0){
        float x = s + bg[0];
        unsigned char a = (depth == 0) ? (unsigned char)1 : eprev[row >> 1];
        e[row] = (unsigned char)((x > 0.f) && a);
    }
}

// ---- pool: pooled = bf16(agg / count) ----
__global__ void pool_k(const float* __restrict__ agg,
                       const unsigned char* __restrict__ e0,
                       const unsigned char* __restrict__ e1,
                       const unsigned char* __restrict__ e2,
                       unsigned short* __restrict__ pooled)
{
    int n = blockIdx.x;
    float cnt = 1.f + 2.f * ((float)e0[n] + (float)e1[2*n] + (float)e1[2*n+1]
              + (float)e2[4*n] + (float)e2[4*n+1] + (float)e2[4*n+2] + (float)e2[4*n+3]);
    float inv = 1.f / cnt; // cnt >= 1 so max(cnt, EPS) == cnt
    const float* a = agg + (long)n*512;
    unsigned short* p = pooled + (long)n*512;
    for (int c = threadIdx.x; c < 512; c += 256)
        p[c] = f2bf(a[c] * inv);
}

extern "C" void kernel_launch(void* const* d_in, const int* in_sizes, int n_in,
                              void* d_out, int out_size, void* d_ws, size_t ws_size,
                              hipStream_t stream)
{
    const int*   tokens = (const int*)d_in[0];
    const float* emb    = (const float*)d_in[1];
    const float* Wp     = (const float*)d_in[2];
    const float* bp     = (const float*)d_in[3];
    const float* Wc     = (const float*)d_in[4];
    const float* bc     = (const float*)d_in[5];
    const float* Wg     = (const float*)d_in[6];
    const float* bg     = (const float*)d_in[7];
    const float* dep    = (const float*)d_in[8];
    const float* sib    = (const float*)d_in[9];
    const float* Wout   = (const float*)d_in[10];
    const float* bout   = (const float*)d_in[11];

    if (ws_size < ((size_t)59 << 20)) return; // need ~57 MB scratch

    char* w = (char*)d_ws;
    auto alloc = [&](size_t bytes)->char*{
        char* p = w; w += (bytes + 255) & ~(size_t)255; return p;
    };
    unsigned short* WpT_h  = (unsigned short*)alloc((size_t)512*512*2);
    unsigned short* WpT_l  = (unsigned short*)alloc((size_t)512*512*2);
    unsigned short* WcT_h  = (unsigned short*)alloc((size_t)1024*512*2);
    unsigned short* WcT_l  = (unsigned short*)alloc((size_t)1024*512*2);
    unsigned short* WoutT  = (unsigned short*)alloc((size_t)32000*512*2);
    float*          nodes0 = (float*)alloc((size_t)4096*512*4);
    float*          agg    = (float*)alloc((size_t)4096*512*4);
    unsigned short* pooled = (unsigned short*)alloc((size_t)4096*512*2);
    unsigned char*  e0     = (unsigned char*)alloc(4096);
    unsigned char*  e1     = (unsigned char*)alloc(8192);
    unsigned char*  e2     = (unsigned char*)alloc(16384);

    // nodes1/nodes2 live inside d_out (524 MB fp32) — dead before final GEMM writes
    float* nodes1 = (float*)d_out;                               // 16.8 MB
    float* nodes2 = (float*)((char*)d_out + ((size_t)64 << 20)); // 33.6 MB
    float* out    = (float*)d_out;

    prep_split16_T<<<dim3(512/32,   512/32), 256, 0, stream>>>(Wp,   WpT_h, WpT_l, 512, 512);
    prep_split16_T<<<dim3(1024/32,  512/32), 256, 0, stream>>>(Wc,   WcT_h, WcT_l, 512, 1024);
    prep_bf16_T   <<<dim3(32000/32, 512/32), 256, 0, stream>>>(Wout, WoutT, 512, 32000);

    // h0 = emb[tok] @ Wp + bp  -> nodes0 (fp32), agg init
    gemm_k<0,0><<<dim3(32, 4), 256, 0, stream>>>(nullptr, nullptr, WpT_h, WpT_l, bp,
        tokens, emb, nullptr, nullptr, nullptr, agg, nodes0, nullptr, 512);

    gate_k<<<4096/4, 256, 0, stream>>>(nodes0, Wg, bg, dep + 0, nullptr, e0, 0);

    gemm_k<1,0><<<dim3(32, 8), 256, 0, stream>>>(nullptr, nodes0, WcT_h, WcT_l, bc,
        nullptr, nullptr, sib, e0, nodes1, agg, nullptr, nullptr, 1024);

    gate_k<<<8192/4, 256, 0, stream>>>(nodes1, Wg, bg, dep + 512, e0, e1, 1);

    gemm_k<1,1><<<dim3(64, 8), 256, 0, stream>>>(nullptr, nodes1, WcT_h, WcT_l, bc,
        nullptr, nullptr, sib, e1, nodes2, agg, nullptr, nullptr, 1024);

    gate_k<<<16384/4, 256, 0, stream>>>(nodes2, Wg, bg, dep + 1024, e1, e2, 2);

    gemm_k<1,2><<<dim3(128, 8), 256, 0, stream>>>(nullptr, nodes2, WcT_h, WcT_l, bc,
        nullptr, nullptr, sib, e2, nullptr, agg, nullptr, nullptr, 1024);

    pool_k<<<4096, 256, 0, stream>>>(agg, e0, e1, e2, pooled);

    // logits = pooled @ Wout + bout (bf16 MFMA, fp32 out)
    gemm_k<2,0><<<dim3(32, 250), 256, 0, stream>>>(pooled, nullptr, WoutT, nullptr, bout,
        nullptr, nullptr, nullptr, nullptr, nullptr, nullptr, nullptr, out, 32000);
}